// Round 10
// baseline (1702.248 us; speedup 1.0000x reference)
//
#include <hip/hip_runtime.h>

constexpr int CAP = 128;   // max nnz per adjacency row (lambda<=22.5, Poisson-safe)
constexpr int RS_INV = 1, RS_RSQRT = 2, CS_RSQRT = 4, FINALIZE = 8;

struct BuildSeg { const float* M; long ldm; int rows; int cols; int col_off;
                  int* idx; int* cnt; };
struct LinJob  { const float* X; const float* X2; float pa, pb; int rows; int K;
                 const float* W; const float* bias; float* out; float* out2; };
struct SpmmJob { const int* idx; const int* cnt; int rows; int mod;
                 const float* X; float* out; float* acc; const float* init;
                 float* fin; int flags; };
struct AttnJob { const float* X; int rows; const float* W; const float* B;
                 const float* H; float* s; int* ctr; float* lse; int nblk; };

// segment indices in the generic stage kernel
enum { SEG_ZERO = 0, SEG_B0 = 1, SEG_B1, SEG_B2, SEG_B3, SEG_SCAT = 5,
       SEG_SP0 = 6, SEG_SP1 = 7, SEG_LIN0 = 8, SEG_LIN1, SEG_LIN2, SEG_LIN3,
       SEG_AT0 = 12, SEG_AT1, SEG_AT2,
       NSEG = 15 };

struct Stage {
    int e[NSEG];                                  // prefix block-range ends
    int nZero; int* zeroPtr; double* stats; int* actr;
    BuildSeg bs[4];
    int scatterTop; int* sIdx; int* sCnt;
    SpmmJob sp[2];
    LinJob lin[4];
    AttnJob at[3];
};

union SharedU {
    float Ws[32 * 128];                           // 16 KB (lin / attn)
    float red[256];                               // reductions
};

// ---------------- device helpers ----------------

// float4 row scan: cols must be /4 (1500, 4500 both are)
__device__ __forceinline__ void build_unit(const BuildSeg& s, int lb)
{
    int row = lb * 4 + (threadIdx.x >> 6);
    if (row >= s.rows) return;
    int lane = threadIdx.x & 63;
    const float4* p4 = (const float4*)(s.M + (long)row * s.ldm);
    int* ri = s.idx + (long)row * CAP;
    int nv = s.cols >> 2;
    unsigned long long below = (1ULL << lane) - 1ULL;
    if (lane == 63) below = 0x7fffffffffffffffULL;
    int base = 0;
    for (int j0 = 0; j0 < nv; j0 += 64) {
        int jj = j0 + lane;
        float4 v = make_float4(0.f, 0.f, 0.f, 0.f);
        if (jj < nv) v = p4[jj];
        unsigned long long m0 = __ballot(v.x == 1.0f);
        unsigned long long m1 = __ballot(v.y == 1.0f);
        unsigned long long m2 = __ballot(v.z == 1.0f);
        unsigned long long m3 = __ballot(v.w == 1.0f);
        int pre = (int)(__popcll(m0 & below) + __popcll(m1 & below)
                      + __popcll(m2 & below) + __popcll(m3 & below));
        int o = base + pre;
        int cbase = (jj << 2) + s.col_off;
        if (v.x == 1.0f) { if (o < CAP) ri[o] = cbase;     ++o; }
        if (v.y == 1.0f) { if (o < CAP) ri[o] = cbase + 1; ++o; }
        if (v.z == 1.0f) { if (o < CAP) ri[o] = cbase + 2; ++o; }
        if (v.w == 1.0f) { if (o < CAP) ri[o] = cbase + 3; ++o; }
        base += (int)(__popcll(m0) + __popcll(m1) + __popcll(m2) + __popcll(m3));
    }
    if (lane == 0) s.cnt[row] = base < CAP ? base : CAP;
}

__device__ __forceinline__ void scatter_unit(int* idx, int* cnt, int topRows, int lb)
{
    int row = lb * 4 + (threadIdx.x >> 6);
    if (row >= topRows) return;
    int lane = threadIdx.x & 63;
    int n = cnt[row];
    const int* ri = idx + (long)row * CAP;
    for (int k = lane; k < n; k += 64) {
        int j = ri[k];
        int pos = atomicAdd(&cnt[j], 1);
        if (pos < CAP) idx[(long)j * CAP + pos] = row;
    }
}

// float4 gather, 8 rows per 256-thread block, 4-wide MLP
__device__ __forceinline__ void spmm_tile(const SpmmJob& j, int lb)
{
    int c4 = threadIdx.x & 31;
    int row = lb * 8 + (threadIdx.x >> 5);
    if (row >= j.rows) return;
    int r_loc = row, xoff = 0;
    if (row >= j.mod) { r_loc = row - j.mod; xoff = j.mod; }
    int n = j.cnt[r_loc];
    const int* ri = j.idx + (long)r_loc * CAP;
    const float4* X4 = (const float4*)j.X;
    const bool csq = (j.flags & CS_RSQRT) != 0;
    float ax = 0.f, ay = 0.f, az = 0.f, aw = 0.f;
    int k = 0;
    for (; k + 4 <= n; k += 4) {
        int c0 = ri[k], c1 = ri[k + 1], c2 = ri[k + 2], c3 = ri[k + 3];
        float4 x0 = X4[(long)(c0 + xoff) * 32 + c4];
        float4 x1 = X4[(long)(c1 + xoff) * 32 + c4];
        float4 x2 = X4[(long)(c2 + xoff) * 32 + c4];
        float4 x3 = X4[(long)(c3 + xoff) * 32 + c4];
        float s0 = 1.0f, s1 = 1.0f, s2 = 1.0f, s3 = 1.0f;
        if (csq) {
            int n0 = j.cnt[c0], n1 = j.cnt[c1], n2 = j.cnt[c2], n3 = j.cnt[c3];
            s0 = (n0 > 0) ? rsqrtf((float)n0) : 0.0f;
            s1 = (n1 > 0) ? rsqrtf((float)n1) : 0.0f;
            s2 = (n2 > 0) ? rsqrtf((float)n2) : 0.0f;
            s3 = (n3 > 0) ? rsqrtf((float)n3) : 0.0f;
        }
        ax += (x0.x * s0 + x1.x * s1) + (x2.x * s2 + x3.x * s3);
        ay += (x0.y * s0 + x1.y * s1) + (x2.y * s2 + x3.y * s3);
        az += (x0.z * s0 + x1.z * s1) + (x2.z * s2 + x3.z * s3);
        aw += (x0.w * s0 + x1.w * s1) + (x2.w * s2 + x3.w * s3);
    }
    for (; k < n; ++k) {
        int c0 = ri[k];
        float4 x0 = X4[(long)(c0 + xoff) * 32 + c4];
        float s0 = 1.0f;
        if (csq) {
            int n0 = j.cnt[c0];
            s0 = (n0 > 0) ? rsqrtf((float)n0) : 0.0f;
        }
        ax += x0.x * s0; ay += x0.y * s0; az += x0.z * s0; aw += x0.w * s0;
    }
    float rs = 1.0f;
    if (j.flags & RS_INV)        rs = (n > 0) ? 1.0f / (float)n : 0.0f;
    else if (j.flags & RS_RSQRT) rs = (n > 0) ? rsqrtf((float)n) : 0.0f;
    float4 v = make_float4(ax * rs, ay * rs, az * rs, aw * rs);
    long o = (long)row * 32 + c4;
    if (j.flags & FINALIZE) {
        float4 acc = ((const float4*)j.acc)[o];
        ((float4*)j.fin)[o] = make_float4((acc.x + v.x) * 0.25f, (acc.y + v.y) * 0.25f,
                                          (acc.z + v.z) * 0.25f, (acc.w + v.w) * 0.25f);
    } else {
        ((float4*)j.out)[o] = v;
        if (j.acc) {
            float4 base = j.init ? ((const float4*)j.init)[o] : ((const float4*)j.acc)[o];
            ((float4*)j.acc)[o] = make_float4(base.x + v.x, base.y + v.y,
                                              base.z + v.z, base.w + v.w);
        }
    }
}

__device__ void lin_tile(const LinJob& j, int lb, float* Ws)
{
    int c = threadIdx.x & 127;
    int row = lb * 2 + (threadIdx.x >> 7);
    if (j.W == nullptr) {                       // premix copy
        if (row < j.rows) {
            long o = (long)row * 128 + c;
            float v = j.pa * j.X[o] + j.pb * j.X2[o];
            j.out[o] = v;
            if (j.out2) j.out2[o] = v;
        }
        return;
    }
    float acc = 0.0f;
    for (int k0 = 0; k0 < j.K; k0 += 32) {
        int chunk = min(32, j.K - k0);
        for (int e = threadIdx.x; e < chunk * 128; e += 256)
            Ws[e] = j.W[(long)(k0 + (e >> 7)) * 128 + (e & 127)];
        __syncthreads();
        if (row < j.rows) {
            const float* xr = j.X + (long)row * j.K + k0;
            const float* x2r = j.X2 ? j.X2 + (long)row * j.K + k0 : nullptr;
            #pragma unroll 4
            for (int kk = 0; kk < chunk; ++kk) {
                float v = xr[kk];
                if (j.X2) v = j.pa * v + j.pb * x2r[kk];
                acc += v * Ws[kk * 128 + c];
            }
        }
        __syncthreads();
    }
    if (row < j.rows) {
        float v = acc + (j.bias ? j.bias[c] : 0.0f);
        j.out[(long)row * 128 + c] = v;
        if (j.out2) j.out2[(long)row * 128 + c] = v;
    }
}

// attn: raw score + last-block lse (fence + device-scope counter; no spinning)
__device__ void attn_tile(const AttnJob& j, int lb, SharedU& sh)
{
    __shared__ float part[4];
    __shared__ int lastFlag;
    int c = threadIdx.x & 127;
    int row = lb * 2 + (threadIdx.x >> 7);
    float acc = 0.0f;
    for (int k0 = 0; k0 < 128; k0 += 32) {
        for (int e = threadIdx.x; e < 32 * 128; e += 256)
            sh.Ws[e] = j.W[(long)(k0 + (e >> 7)) * 128 + (e & 127)];
        __syncthreads();
        if (row < j.rows) {
            const float* xr = j.X + (long)row * 128 + k0;
            #pragma unroll 4
            for (int kk = 0; kk < 32; ++kk)
                acc += xr[kk] * sh.Ws[kk * 128 + c];
        }
        __syncthreads();
    }
    float v = 0.0f;
    if (row < j.rows) v = fmaxf(acc + j.B[c], 0.0f) * j.H[c];
    for (int o = 32; o > 0; o >>= 1) v += __shfl_down(v, o, 64);
    if ((threadIdx.x & 63) == 0) part[threadIdx.x >> 6] = v;
    __syncthreads();
    if (threadIdx.x == 0 && row < j.rows)   j.s[row] = part[0] + part[1];
    if (threadIdx.x == 128 && row < j.rows) j.s[row] = part[2] + part[3];
    // ---- last arriving block computes lse (bit-identical to old softmax) ----
    __threadfence();
    __syncthreads();
    if (threadIdx.x == 0)
        lastFlag = (atomicAdd(j.ctr, 1) == j.nblk - 1) ? 1 : 0;
    __syncthreads();
    if (!lastFlag) return;
    __threadfence();
    int t = threadIdx.x, n = j.rows;
    float* red = sh.red;
    float m = -3.4e38f;
    for (int i = t; i < n; i += 256) m = fmaxf(m, j.s[i]);
    red[t] = m; __syncthreads();
    for (int o = 128; o > 0; o >>= 1) {
        if (t < o) red[t] = fmaxf(red[t], red[t + o]);
        __syncthreads();
    }
    m = red[0];
    __syncthreads();
    float sum = 0.0f;
    for (int i = t; i < n; i += 256) sum += expf(j.s[i] - m);
    red[t] = sum; __syncthreads();
    for (int o = 128; o > 0; o >>= 1) {
        if (t < o) red[t] += red[t + o];
        __syncthreads();
    }
    if (t == 0) *j.lse = m + logf(red[0]);
}

// ---------------- generic stage kernel: grid partitioned by segment --------
__global__ __launch_bounds__(256)
void k_stage(Stage s)
{
    __shared__ SharedU sh;
    int b = blockIdx.x;
    if (b < s.e[SEG_ZERO]) {
        int i = b * 256 + threadIdx.x;
        if (i < s.nZero) s.zeroPtr[i] = 0;
        if (b == 0 && threadIdx.x < 2 && s.stats) s.stats[threadIdx.x] = 0.0;
        if (b == 0 && threadIdx.x >= 8 && threadIdx.x < 13 && s.actr)
            s.actr[threadIdx.x - 8] = 0;
        return;
    }
    if (b < s.e[SEG_B0]) { build_unit(s.bs[0], b - s.e[SEG_B0 - 1]); return; }
    if (b < s.e[SEG_B1]) { build_unit(s.bs[1], b - s.e[SEG_B1 - 1]); return; }
    if (b < s.e[SEG_B2]) { build_unit(s.bs[2], b - s.e[SEG_B2 - 1]); return; }
    if (b < s.e[SEG_B3]) { build_unit(s.bs[3], b - s.e[SEG_B3 - 1]); return; }
    if (b < s.e[SEG_SCAT]) { scatter_unit(s.sIdx, s.sCnt, s.scatterTop, b - s.e[SEG_SCAT - 1]); return; }
    if (b < s.e[SEG_SP0]) { spmm_tile(s.sp[0], b - s.e[SEG_SP0 - 1]); return; }
    if (b < s.e[SEG_SP1]) { spmm_tile(s.sp[1], b - s.e[SEG_SP1 - 1]); return; }
    if (b < s.e[SEG_LIN0]) { lin_tile(s.lin[0], b - s.e[SEG_LIN0 - 1], sh.Ws); return; }
    if (b < s.e[SEG_LIN1]) { lin_tile(s.lin[1], b - s.e[SEG_LIN1 - 1], sh.Ws); return; }
    if (b < s.e[SEG_LIN2]) { lin_tile(s.lin[2], b - s.e[SEG_LIN2 - 1], sh.Ws); return; }
    if (b < s.e[SEG_LIN3]) { lin_tile(s.lin[3], b - s.e[SEG_LIN3 - 1], sh.Ws); return; }
    if (b < s.e[SEG_AT0]) { attn_tile(s.at[0], b - s.e[SEG_AT0 - 1], sh); return; }
    if (b < s.e[SEG_AT1]) { attn_tile(s.at[1], b - s.e[SEG_AT1 - 1], sh); return; }
    if (b < s.e[SEG_AT2]) { attn_tile(s.at[2], b - s.e[SEG_AT2 - 1], sh); return; }
}

// ---------------- y GEMM with fused blend (fin) + stats ----------------
// lse layout: 0=w_drel, 1=w_prel, 2=w_dsim, 3=w_drug(int), 4=w_pro(int)
__global__ __launch_bounds__(256)
void k_ygemm(const float* __restrict__ wdI, const float* __restrict__ wdR,
             const float* __restrict__ wdS, const float* __restrict__ wpI,
             const float* __restrict__ wpR, const float* __restrict__ lse,
             const float* __restrict__ eiI, const float* __restrict__ eiR,
             const float* __restrict__ eiS,
             const float* __restrict__ pjI, const float* __restrict__ pjR,
             int M, int N, float* __restrict__ y, double* __restrict__ stats)
{
    __shared__ float Ast[32][65];
    __shared__ float Bst[32][65];
    __shared__ float wa[64], wb[64], wc[64], pa[64];
    __shared__ double r1[256];
    __shared__ double r2[256];
    int i0 = blockIdx.y * 64, j0 = blockIdx.x * 64;
    // per-row blend weights (same formula as the old k_fin, raw - lse = softmaxed)
    if (threadIdx.x < 64) {
        int i = i0 + threadIdx.x;
        if (i < M) {
            float aL = wdI[i] - lse[3], bL = wdR[i] - lse[0], cL = wdS[i] - lse[2];
            float x = aL / (aL + bL + cL);
            float yv = bL / (x + bL + cL);
            wa[threadIdx.x] = x; wb[threadIdx.x] = yv; wc[threadIdx.x] = 1.0f - x - yv;
        }
    } else if (threadIdx.x < 128) {
        int j = j0 + (threadIdx.x - 64);
        if (j < N) {
            float u = wpI[j] - lse[4], v = wpR[j] - lse[1];
            pa[threadIdx.x - 64] = u / (u + v);
        }
    }
    __syncthreads();
    int tx = threadIdx.x & 15, ty = threadIdx.x >> 4;
    float acc[4][4] = {};
    for (int k0 = 0; k0 < 128; k0 += 32) {
        for (int e = threadIdx.x; e < 64 * 32; e += 256) {
            int r = e >> 5, kk = e & 31;
            int ia = i0 + r, jb = j0 + r;
            long oa = (long)ia * 128 + k0 + kk;
            long ob = (long)jb * 128 + k0 + kk;
            Ast[kk][r] = (ia < M)
                ? wa[r] * eiI[oa] + wb[r] * eiR[oa] + wc[r] * eiS[oa] : 0.0f;
            Bst[kk][r] = (jb < N)
                ? pa[r] * pjI[ob] + (1.0f - pa[r]) * pjR[ob] : 0.0f;
        }
        __syncthreads();
        #pragma unroll 8
        for (int kk = 0; kk < 32; ++kk) {
            float a0 = Ast[kk][ty];      float a1 = Ast[kk][ty + 16];
            float a2 = Ast[kk][ty + 32]; float a3 = Ast[kk][ty + 48];
            float b0 = Bst[kk][tx];      float b1 = Bst[kk][tx + 16];
            float b2 = Bst[kk][tx + 32]; float b3 = Bst[kk][tx + 48];
            acc[0][0] += a0 * b0; acc[0][1] += a0 * b1; acc[0][2] += a0 * b2; acc[0][3] += a0 * b3;
            acc[1][0] += a1 * b0; acc[1][1] += a1 * b1; acc[1][2] += a1 * b2; acc[1][3] += a1 * b3;
            acc[2][0] += a2 * b0; acc[2][1] += a2 * b1; acc[2][2] += a2 * b2; acc[2][3] += a2 * b3;
            acc[3][0] += a3 * b0; acc[3][1] += a3 * b1; acc[3][2] += a3 * b2; acc[3][3] += a3 * b3;
        }
        __syncthreads();
    }
    double s1 = 0.0, s2 = 0.0;
    #pragma unroll
    for (int q = 0; q < 4; ++q) {
        int i = i0 + ty + 16 * q;
        if (i < M) {
            #pragma unroll
            for (int p = 0; p < 4; ++p) {
                int j = j0 + tx + 16 * p;
                if (j < N) {
                    float v = acc[q][p];
                    y[(long)i * N + j] = v;
                    s1 += v; s2 += (double)v * v;
                }
            }
        }
    }
    r1[threadIdx.x] = s1; r2[threadIdx.x] = s2;
    __syncthreads();
    for (int o = 128; o > 0; o >>= 1) {
        if (threadIdx.x < o) {
            r1[threadIdx.x] += r1[threadIdx.x + o];
            r2[threadIdx.x] += r2[threadIdx.x + o];
        }
        __syncthreads();
    }
    if (threadIdx.x == 0) {
        atomicAdd(&stats[0], r1[0]);
        atomicAdd(&stats[1], r2[0]);
    }
}

__global__ void k_sigmoid(const float* __restrict__ y, const double* __restrict__ stats,
                          long n4, float* __restrict__ out)
{
    long i = (long)blockIdx.x * 256 + threadIdx.x;
    if (i >= n4) return;
    double nd = (double)(n4 * 4);
    double mean = stats[0] / nd;
    double var = (stats[1] - nd * mean * mean) / (nd - 1.0);
    if (var < 1e-30) var = 1e-30;
    float inv = (float)(1.0 / sqrt(var));
    float mu = (float)mean;
    float4 v = ((const float4*)y)[i];
    v.x = 1.0f / (1.0f + expf(-((v.x - mu) * inv)));
    v.y = 1.0f / (1.0f + expf(-((v.y - mu) * inv)));
    v.z = 1.0f / (1.0f + expf(-((v.z - mu) * inv)));
    v.w = 1.0f / (1.0f + expf(-((v.w - mu) * inv)));
    ((float4*)out)[i] = v;
}

// ==================================================================
extern "C" void kernel_launch(void* const* d_in, const int* in_sizes, int n_in,
                              void* d_out, int out_size, void* d_ws, size_t ws_size,
                              hipStream_t stream)
{
    constexpr int D = 1500, P = 4500, E = 128;
    constexpr int NB = D + P;          // 6000 bipartite rows
    constexpr int NR = D + P + D;      // 7500 stacked rel rows [A2; A3; A4]
    constexpr long ALD = 6000;
    constexpr long ASZ = 36000000L;

    const float* A    = (const float*)d_in[0];
    const float* drug_structure    = (const float*)d_in[1];
    const float* protein_structure = (const float*)d_in[2];
    const float* lin_drug_w = (const float*)d_in[3];
    const float* lin_drug_b = (const float*)d_in[4];
    const float* lin_pro_w  = (const float*)d_in[5];
    const float* lin_pro_b  = (const float*)d_in[6];
    const float* p_weight   = (const float*)d_in[7];
    const float* d_weight_i = (const float*)d_in[8];
    const float* pd_weight_p = (const float*)d_in[9];
    const float* pd_weight_d = (const float*)d_in[10];
    const float* dp_weight_p = (const float*)d_in[11];
    const float* WA_drug = (const float*)d_in[12];
    const float* BA_drug = (const float*)d_in[13];
    const float* HA_drug = (const float*)d_in[14];
    const float* WB_drug = (const float*)d_in[15];
    const float* BB_drug = (const float*)d_in[16];
    const float* HB_drug = (const float*)d_in[17];
    const float* WA_pro = (const float*)d_in[18];
    const float* BA_pro = (const float*)d_in[19];
    const float* HA_pro = (const float*)d_in[20];
    const float* WB_pro = (const float*)d_in[21];
    const float* BB_pro = (const float*)d_in[22];
    const float* HB_pro = (const float*)d_in[23];
    const float* WA_sim = (const float*)d_in[24];
    const float* BA_sim = (const float*)d_in[25];
    const float* HA_sim = (const float*)d_in[26];
    // d_in[27] = layer (int), fixed 3.

    const float* Rp  = A + 1500;                          // [D x P]   ld 6000
    const float* A2p = A + 2 * ASZ;                       // [D x D]
    const float* A3p = A + 3 * ASZ + 1500 * ALD + 1500;   // [P x P]
    const float* A4p = A + 4 * ASZ;                       // [D x D]

    char* wsbase = (char*)d_ws;
    size_t off = 0;
    auto alloc = [&](size_t bytes) -> void* {
        off = (off + 255) & ~(size_t)255;
        void* p = wsbase + off;
        off += bytes;
        return p;
    };
    int*   idx_bip  = (int*)alloc((size_t)NB * CAP * 4);
    int*   cnt_bip  = (int*)alloc((size_t)NB * 4);
    int*   idx_rel  = (int*)alloc((size_t)NR * CAP * 4);
    int*   cnt_rel  = (int*)alloc((size_t)NR * 4);
    float* str_s    = (float*)alloc((size_t)NR * E * 4);
    float* nei_s    = (float*)alloc((size_t)NR * E * 4);
    float* cur_s    = (float*)alloc((size_t)NR * E * 4);
    float* nxt_s    = (float*)alloc((size_t)NR * E * 4);
    float* acc_s    = (float*)alloc((size_t)NR * E * 4);
    float* emb_s    = (float*)alloc((size_t)NR * E * 4);
    float* tem_s    = (float*)alloc((size_t)NB * E * 4);
    float* big_cur  = (float*)alloc((size_t)2 * NB * E * 4);
    float* big_nxt  = (float*)alloc((size_t)2 * NB * E * 4);
    float* big_acc  = (float*)alloc((size_t)2 * NB * E * 4);
    float* int_s    = (float*)alloc((size_t)2 * NB * E * 4);
    float* W2       = (float*)alloc((size_t)E * E * 4);
    float* w_drug = (float*)alloc(D * 4);
    float* w_drel = (float*)alloc(D * 4);
    float* w_dsim = (float*)alloc(D * 4);
    float* w_pro  = (float*)alloc(P * 4);
    float* w_prel = (float*)alloc(P * 4);
    float* ybuf    = (float*)alloc((size_t)D * P * 4);
    double* stats  = (double*)alloc(2 * sizeof(double));
    int*   actr    = (int*)alloc(5 * 4);
    float* lseArr  = (float*)alloc(5 * 4);
    (void)ws_size; (void)in_sizes; (void)n_in; (void)out_size;

    float* dru_str = str_s;
    float* pro_str = str_s + (size_t)D * E;
    float* dru_rel_emb = emb_s;
    float* pro_rel_emb = emb_s + (size_t)D * E;
    float* dru_sim_emb = emb_s + (size_t)NB * E;
    float* dru_tem = tem_s;
    float* pro_tem = tem_s + (size_t)D * E;
    float* dru_int = int_s;
    float* pro_int = int_s + (size_t)(NB + D) * E;

    long nD = (long)D * E;

    auto launch_stage = [&](Stage& s, const int* sz) {
        int tot = 0;
        for (int i = 0; i < NSEG; ++i) { tot += sz[i]; s.e[i] = tot; }
        k_stage<<<tot, 256, 0, stream>>>(s);
    };

    // ---- Stage 1: zero counters/stats/attn-counters + build 4 CSRs + projections + W2 ----
    {
        Stage s = {};
        int sz[NSEG] = {};
        sz[SEG_ZERO] = (P + 255) / 256;
        s.nZero = P; s.zeroPtr = cnt_bip + D; s.stats = stats; s.actr = actr;
        s.bs[0] = { Rp,  ALD, D, P, D,  idx_bip, cnt_bip };                        sz[SEG_B0] = (D + 3) / 4;
        s.bs[1] = { A2p, ALD, D, D, 0,  idx_rel, cnt_rel };                        sz[SEG_B1] = (D + 3) / 4;
        s.bs[2] = { A3p, ALD, P, P, D,  idx_rel + (size_t)D * CAP,  cnt_rel + D }; sz[SEG_B2] = (P + 3) / 4;
        s.bs[3] = { A4p, ALD, D, D, NB, idx_rel + (size_t)NB * CAP, cnt_rel + NB };sz[SEG_B3] = (D + 3) / 4;
        s.lin[0] = { drug_structure, nullptr, 0, 0, D, 160, lin_drug_w, lin_drug_b,
                     dru_str, str_s + (size_t)NB * E };                            sz[SEG_LIN0] = (D + 1) / 2;
        s.lin[1] = { protein_structure, nullptr, 0, 0, P, 512, lin_pro_w, lin_pro_b,
                     pro_str, nullptr };                                           sz[SEG_LIN1] = (P + 1) / 2;
        s.lin[2] = { dp_weight_p, nullptr, 0, 0, E, E, pd_weight_d, nullptr, W2, nullptr };
                                                                                   sz[SEG_LIN2] = (E + 1) / 2;
        launch_stage(s, sz);
    }
    // ---- Stage 2: scatter transpose + rel neighbor means + rel GCN inits ----
    {
        Stage s = {};
        int sz[NSEG] = {};
        s.scatterTop = D; s.sIdx = idx_bip; s.sCnt = cnt_bip;                      sz[SEG_SCAT] = (D + 3) / 4;
        s.sp[0] = { idx_rel, cnt_rel, NR, NR, str_s, nei_s, nullptr, nullptr, nullptr, RS_INV };
                                                                                   sz[SEG_SP0] = (NR + 7) / 8;
        s.lin[0] = { dru_str, nullptr, 0, 0, D, E, d_weight_i, nullptr,
                     cur_s, cur_s + (size_t)NB * E };                              sz[SEG_LIN0] = (D + 1) / 2;
        s.lin[1] = { pro_str, nullptr, 0, 0, P, E, p_weight, nullptr,
                     cur_s + (size_t)D * E, nullptr };                             sz[SEG_LIN1] = (P + 1) / 2;
        launch_stage(s, sz);
    }
    // ---- Stage 3: rel L1 || bipartite neighbor means ----
    {
        Stage s = {};
        int sz[NSEG] = {};
        s.sp[0] = { idx_rel, cnt_rel, NR, NR, cur_s, nxt_s, acc_s, cur_s, nullptr,
                    RS_RSQRT | CS_RSQRT };                                         sz[SEG_SP0] = (NR + 7) / 8;
        s.sp[1] = { idx_bip, cnt_bip, NB, NB, nei_s, tem_s, nullptr, nullptr, nullptr,
                    RS_INV };                                                      sz[SEG_SP1] = (NB + 7) / 8;
        launch_stage(s, sz);
    }
    // ---- Stage 4: rel L2 || bipartite GCN inits ----
    {
        Stage s = {};
        int sz[NSEG] = {};
        s.sp[0] = { idx_rel, cnt_rel, NR, NR, nxt_s, cur_s, acc_s, nullptr, nullptr,
                    RS_RSQRT | CS_RSQRT };                                         sz[SEG_SP0] = (NR + 7) / 8;
        s.lin[0] = { dru_str, nullptr, 0, 0, D, E, pd_weight_d, nullptr, big_cur, nullptr };
                                                                                   sz[SEG_LIN0] = (D + 1) / 2;
        s.lin[1] = { pro_str, pro_tem, 0.8f, 0.2f, P, E, W2, nullptr, big_cur + nD, nullptr };
                                                                                   sz[SEG_LIN1] = (P + 1) / 2;
        s.lin[2] = { dru_str, dru_tem, 0.8f, 0.2f, D, E, nullptr, nullptr,
                     big_cur + (size_t)NB * E, nullptr };                          sz[SEG_LIN2] = (D + 1) / 2;
        s.lin[3] = { pro_str, nullptr, 0, 0, P, E, pd_weight_p, nullptr,
                     big_cur + (size_t)(NB + D) * E, nullptr };                    sz[SEG_LIN3] = (P + 1) / 2;
        launch_stage(s, sz);
    }
    // ---- Stage 5: bip L1 || rel L3 (finalize -> emb) ----
    {
        Stage s = {};
        int sz[NSEG] = {};
        s.sp[0] = { idx_bip, cnt_bip, 2 * NB, NB, big_cur, big_nxt, big_acc, big_cur,
                    nullptr, RS_RSQRT | CS_RSQRT };                                sz[SEG_SP0] = (2 * NB + 7) / 8;
        s.sp[1] = { idx_rel, cnt_rel, NR, NR, cur_s, nullptr, acc_s, nullptr, emb_s,
                    RS_RSQRT | CS_RSQRT | FINALIZE };                              sz[SEG_SP1] = (NR + 7) / 8;
        launch_stage(s, sz);
    }
    // ---- Stage 6: bip L2 || rel attention scores (+lse via last block) ----
    {
        Stage s = {};
        int sz[NSEG] = {};
        s.sp[0] = { idx_bip, cnt_bip, 2 * NB, NB, big_nxt, big_cur, big_acc, nullptr,
                    nullptr, RS_RSQRT | CS_RSQRT };                                sz[SEG_SP0] = (2 * NB + 7) / 8;
        s.at[0] = { dru_rel_emb, D, WB_drug, BB_drug, HB_drug, w_drel,
                    actr + 0, lseArr + 0, (D + 1) / 2 };                           sz[SEG_AT0] = (D + 1) / 2;
        s.at[1] = { pro_rel_emb, P, WB_pro,  BB_pro,  HB_pro,  w_prel,
                    actr + 1, lseArr + 1, (P + 1) / 2 };                           sz[SEG_AT1] = (P + 1) / 2;
        s.at[2] = { dru_sim_emb, D, WA_sim,  BA_sim,  HA_sim,  w_dsim,
                    actr + 2, lseArr + 2, (D + 1) / 2 };                           sz[SEG_AT2] = (D + 1) / 2;
        launch_stage(s, sz);
    }
    // ---- Stage 7: bip L3 (finalize -> int) ----
    {
        Stage s = {};
        int sz[NSEG] = {};
        s.sp[0] = { idx_bip, cnt_bip, 2 * NB, NB, big_cur, nullptr, big_acc, nullptr,
                    int_s, RS_RSQRT | CS_RSQRT | FINALIZE };                       sz[SEG_SP0] = (2 * NB + 7) / 8;
        launch_stage(s, sz);
    }
    // ---- Stage 8: int attention scores (+lse via last block) ----
    {
        Stage s = {};
        int sz[NSEG] = {};
        s.at[0] = { dru_int, D, WA_drug, BA_drug, HA_drug, w_drug,
                    actr + 3, lseArr + 3, (D + 1) / 2 };                           sz[SEG_AT0] = (D + 1) / 2;
        s.at[1] = { pro_int, P, WA_pro,  BA_pro,  HA_pro,  w_pro,
                    actr + 4, lseArr + 4, (P + 1) / 2 };                           sz[SEG_AT1] = (P + 1) / 2;
        launch_stage(s, sz);
    }
    // ---- y GEMM with fused blend + stats, then standardize + sigmoid ----
    dim3 yg((P + 63) / 64, (D + 63) / 64);
    k_ygemm<<<yg, 256, 0, stream>>>(w_drug, w_drel, w_dsim, w_pro, w_prel, lseArr,
                                    dru_int, dru_rel_emb, dru_sim_emb,
                                    pro_int, pro_rel_emb,
                                    D, P, ybuf, stats);
    long n4 = ((long)D * P) >> 2;
    k_sigmoid<<<(int)((n4 + 255) / 256), 256, 0, stream>>>(ybuf, stats, n4, (float*)d_out);
}

// Round 11
// 1307.063 us; speedup vs baseline: 1.3023x; 1.3023x over previous
//
#include <hip/hip_runtime.h>

constexpr int CAP = 128;   // max nnz per adjacency row (lambda<=22.5, Poisson-safe)
constexpr int RS_INV = 1, RS_RSQRT = 2, CS_RSQRT = 4, FINALIZE = 8;

struct BuildSeg { const float* M; long ldm; int rows; int cols; int col_off;
                  int* idx; int* cnt; };
struct LinJob  { const float* X; const float* X2; float pa, pb; int rows; int K;
                 const float* W; const float* bias; float* out; float* out2; };
struct SpmmJob { const int* idx; const int* cnt; int rows; int mod;
                 const float* X; float* out; float* acc; const float* init;
                 float* fin; int flags; };
struct AttnJob { const float* X; int rows; const float* W; const float* B;
                 const float* H; float* s; };

// segment indices in the generic stage kernel
enum { SEG_ZERO = 0, SEG_B0 = 1, SEG_B1, SEG_B2, SEG_B3, SEG_SCAT = 5,
       SEG_SP0 = 6, SEG_SP1 = 7, SEG_LIN0 = 8, SEG_LIN1, SEG_LIN2, SEG_LIN3,
       SEG_AT0 = 12, SEG_AT1, SEG_AT2, SEG_SM0 = 15, SEG_SM1, SEG_SM2,
       NSEG = 18 };

struct Stage {
    int e[NSEG];                                  // prefix block-range ends
    int nZero; int* zeroPtr; double* stats;
    BuildSeg bs[4];
    int scatterTop; int* sIdx; int* sCnt;
    SpmmJob sp[2];
    LinJob lin[4];
    AttnJob at[3];
    float* smv[3]; int smn[3];
};

union SharedU {
    float Ws[32 * 128];                           // 16 KB (lin / attn)
    float red[256];                               // softmax
};

// ---------------- device helpers (numerics identical to R9) ----------------

// float4 row scan: cols must be /4 (1500, 4500 both are)
__device__ __forceinline__ void build_unit(const BuildSeg& s, int lb)
{
    int row = lb * 4 + (threadIdx.x >> 6);
    if (row >= s.rows) return;
    int lane = threadIdx.x & 63;
    const float4* p4 = (const float4*)(s.M + (long)row * s.ldm);
    int* ri = s.idx + (long)row * CAP;
    int nv = s.cols >> 2;
    unsigned long long below = (1ULL << lane) - 1ULL;
    if (lane == 63) below = 0x7fffffffffffffffULL;
    int base = 0;
    for (int j0 = 0; j0 < nv; j0 += 64) {
        int jj = j0 + lane;
        float4 v = make_float4(0.f, 0.f, 0.f, 0.f);
        if (jj < nv) v = p4[jj];
        unsigned long long m0 = __ballot(v.x == 1.0f);
        unsigned long long m1 = __ballot(v.y == 1.0f);
        unsigned long long m2 = __ballot(v.z == 1.0f);
        unsigned long long m3 = __ballot(v.w == 1.0f);
        int pre = (int)(__popcll(m0 & below) + __popcll(m1 & below)
                      + __popcll(m2 & below) + __popcll(m3 & below));
        int o = base + pre;
        int cbase = (jj << 2) + s.col_off;
        if (v.x == 1.0f) { if (o < CAP) ri[o] = cbase;     ++o; }
        if (v.y == 1.0f) { if (o < CAP) ri[o] = cbase + 1; ++o; }
        if (v.z == 1.0f) { if (o < CAP) ri[o] = cbase + 2; ++o; }
        if (v.w == 1.0f) { if (o < CAP) ri[o] = cbase + 3; ++o; }
        base += (int)(__popcll(m0) + __popcll(m1) + __popcll(m2) + __popcll(m3));
    }
    if (lane == 0) s.cnt[row] = base < CAP ? base : CAP;
}

__device__ __forceinline__ void scatter_unit(int* idx, int* cnt, int topRows, int lb)
{
    int row = lb * 4 + (threadIdx.x >> 6);
    if (row >= topRows) return;
    int lane = threadIdx.x & 63;
    int n = cnt[row];
    const int* ri = idx + (long)row * CAP;
    for (int k = lane; k < n; k += 64) {
        int j = ri[k];
        int pos = atomicAdd(&cnt[j], 1);
        if (pos < CAP) idx[(long)j * CAP + pos] = row;
    }
}

// float4 gather, 8 rows per 256-thread block (R9's 2-wide unroll)
__device__ __forceinline__ void spmm_tile(const SpmmJob& j, int lb)
{
    int c4 = threadIdx.x & 31;
    int row = lb * 8 + (threadIdx.x >> 5);
    if (row >= j.rows) return;
    int r_loc = row, xoff = 0;
    if (row >= j.mod) { r_loc = row - j.mod; xoff = j.mod; }
    int n = j.cnt[r_loc];
    const int* ri = j.idx + (long)r_loc * CAP;
    const float4* X4 = (const float4*)j.X;
    const bool csq = (j.flags & CS_RSQRT) != 0;
    float ax = 0.f, ay = 0.f, az = 0.f, aw = 0.f;
    int k = 0;
    for (; k + 2 <= n; k += 2) {
        int c0 = ri[k], c1 = ri[k + 1];
        float4 x0 = X4[(long)(c0 + xoff) * 32 + c4];
        float4 x1 = X4[(long)(c1 + xoff) * 32 + c4];
        float s0 = 1.0f, s1 = 1.0f;
        if (csq) {
            int n0 = j.cnt[c0], n1 = j.cnt[c1];
            s0 = (n0 > 0) ? rsqrtf((float)n0) : 0.0f;
            s1 = (n1 > 0) ? rsqrtf((float)n1) : 0.0f;
        }
        ax += x0.x * s0 + x1.x * s1;
        ay += x0.y * s0 + x1.y * s1;
        az += x0.z * s0 + x1.z * s1;
        aw += x0.w * s0 + x1.w * s1;
    }
    if (k < n) {
        int c0 = ri[k];
        float4 x0 = X4[(long)(c0 + xoff) * 32 + c4];
        float s0 = 1.0f;
        if (csq) {
            int n0 = j.cnt[c0];
            s0 = (n0 > 0) ? rsqrtf((float)n0) : 0.0f;
        }
        ax += x0.x * s0; ay += x0.y * s0; az += x0.z * s0; aw += x0.w * s0;
    }
    float rs = 1.0f;
    if (j.flags & RS_INV)        rs = (n > 0) ? 1.0f / (float)n : 0.0f;
    else if (j.flags & RS_RSQRT) rs = (n > 0) ? rsqrtf((float)n) : 0.0f;
    float4 v = make_float4(ax * rs, ay * rs, az * rs, aw * rs);
    long o = (long)row * 32 + c4;
    if (j.flags & FINALIZE) {
        float4 acc = ((const float4*)j.acc)[o];
        ((float4*)j.fin)[o] = make_float4((acc.x + v.x) * 0.25f, (acc.y + v.y) * 0.25f,
                                          (acc.z + v.z) * 0.25f, (acc.w + v.w) * 0.25f);
    } else {
        ((float4*)j.out)[o] = v;
        if (j.acc) {
            float4 base = j.init ? ((const float4*)j.init)[o] : ((const float4*)j.acc)[o];
            ((float4*)j.acc)[o] = make_float4(base.x + v.x, base.y + v.y,
                                              base.z + v.z, base.w + v.w);
        }
    }
}

__device__ void lin_tile(const LinJob& j, int lb, float* Ws)
{
    int c = threadIdx.x & 127;
    int row = lb * 2 + (threadIdx.x >> 7);
    if (j.W == nullptr) {                       // premix copy
        if (row < j.rows) {
            long o = (long)row * 128 + c;
            float v = j.pa * j.X[o] + j.pb * j.X2[o];
            j.out[o] = v;
            if (j.out2) j.out2[o] = v;
        }
        return;
    }
    float acc = 0.0f;
    for (int k0 = 0; k0 < j.K; k0 += 32) {
        int chunk = min(32, j.K - k0);
        for (int e = threadIdx.x; e < chunk * 128; e += 256)
            Ws[e] = j.W[(long)(k0 + (e >> 7)) * 128 + (e & 127)];
        __syncthreads();
        if (row < j.rows) {
            const float* xr = j.X + (long)row * j.K + k0;
            const float* x2r = j.X2 ? j.X2 + (long)row * j.K + k0 : nullptr;
            #pragma unroll 4
            for (int kk = 0; kk < chunk; ++kk) {
                float v = xr[kk];
                if (j.X2) v = j.pa * v + j.pb * x2r[kk];
                acc += v * Ws[kk * 128 + c];
            }
        }
        __syncthreads();
    }
    if (row < j.rows) {
        float v = acc + (j.bias ? j.bias[c] : 0.0f);
        j.out[(long)row * 128 + c] = v;
        if (j.out2) j.out2[(long)row * 128 + c] = v;
    }
}

__device__ void attn_tile(const AttnJob& j, int lb, float* Ws)
{
    __shared__ float part[4];
    int c = threadIdx.x & 127;
    int row = lb * 2 + (threadIdx.x >> 7);
    float acc = 0.0f;
    for (int k0 = 0; k0 < 128; k0 += 32) {
        for (int e = threadIdx.x; e < 32 * 128; e += 256)
            Ws[e] = j.W[(long)(k0 + (e >> 7)) * 128 + (e & 127)];
        __syncthreads();
        if (row < j.rows) {
            const float* xr = j.X + (long)row * 128 + k0;
            #pragma unroll 4
            for (int kk = 0; kk < 32; ++kk)
                acc += xr[kk] * Ws[kk * 128 + c];
        }
        __syncthreads();
    }
    float v = 0.0f;
    if (row < j.rows) v = fmaxf(acc + j.B[c], 0.0f) * j.H[c];
    for (int o = 32; o > 0; o >>= 1) v += __shfl_down(v, o, 64);
    if ((threadIdx.x & 63) == 0) part[threadIdx.x >> 6] = v;
    __syncthreads();
    if (threadIdx.x == 0 && row < j.rows)   j.s[row] = part[0] + part[1];
    if (threadIdx.x == 128 && row < j.rows) j.s[row] = part[2] + part[3];
}

__device__ void softmax_vec(float* s, int n, float* red)
{
    int t = threadIdx.x;
    float m = -3.4e38f;
    for (int i = t; i < n; i += 256) m = fmaxf(m, s[i]);
    red[t] = m; __syncthreads();
    for (int o = 128; o > 0; o >>= 1) {
        if (t < o) red[t] = fmaxf(red[t], red[t + o]);
        __syncthreads();
    }
    m = red[0];
    __syncthreads();
    float sum = 0.0f;
    for (int i = t; i < n; i += 256) sum += expf(s[i] - m);
    red[t] = sum; __syncthreads();
    for (int o = 128; o > 0; o >>= 1) {
        if (t < o) red[t] += red[t + o];
        __syncthreads();
    }
    float lse = m + logf(red[0]);
    for (int i = t; i < n; i += 256) s[i] -= lse;
}

// ---------------- generic stage kernel: grid partitioned by segment --------
__global__ __launch_bounds__(256)
void k_stage(Stage s)
{
    __shared__ SharedU sh;
    int b = blockIdx.x;
    if (b < s.e[SEG_ZERO]) {
        int i = b * 256 + threadIdx.x;
        if (i < s.nZero) s.zeroPtr[i] = 0;
        if (b == 0 && threadIdx.x < 2 && s.stats) s.stats[threadIdx.x] = 0.0;
        return;
    }
    if (b < s.e[SEG_B0]) { build_unit(s.bs[0], b - s.e[SEG_B0 - 1]); return; }
    if (b < s.e[SEG_B1]) { build_unit(s.bs[1], b - s.e[SEG_B1 - 1]); return; }
    if (b < s.e[SEG_B2]) { build_unit(s.bs[2], b - s.e[SEG_B2 - 1]); return; }
    if (b < s.e[SEG_B3]) { build_unit(s.bs[3], b - s.e[SEG_B3 - 1]); return; }
    if (b < s.e[SEG_SCAT]) { scatter_unit(s.sIdx, s.sCnt, s.scatterTop, b - s.e[SEG_SCAT - 1]); return; }
    if (b < s.e[SEG_SP0]) { spmm_tile(s.sp[0], b - s.e[SEG_SP0 - 1]); return; }
    if (b < s.e[SEG_SP1]) { spmm_tile(s.sp[1], b - s.e[SEG_SP1 - 1]); return; }
    if (b < s.e[SEG_LIN0]) { lin_tile(s.lin[0], b - s.e[SEG_LIN0 - 1], sh.Ws); return; }
    if (b < s.e[SEG_LIN1]) { lin_tile(s.lin[1], b - s.e[SEG_LIN1 - 1], sh.Ws); return; }
    if (b < s.e[SEG_LIN2]) { lin_tile(s.lin[2], b - s.e[SEG_LIN2 - 1], sh.Ws); return; }
    if (b < s.e[SEG_LIN3]) { lin_tile(s.lin[3], b - s.e[SEG_LIN3 - 1], sh.Ws); return; }
    if (b < s.e[SEG_AT0]) { attn_tile(s.at[0], b - s.e[SEG_AT0 - 1], sh.Ws); return; }
    if (b < s.e[SEG_AT1]) { attn_tile(s.at[1], b - s.e[SEG_AT1 - 1], sh.Ws); return; }
    if (b < s.e[SEG_AT2]) { attn_tile(s.at[2], b - s.e[SEG_AT2 - 1], sh.Ws); return; }
    if (b < s.e[SEG_SM0]) { softmax_vec(s.smv[0], s.smn[0], sh.red); return; }
    if (b < s.e[SEG_SM1]) { softmax_vec(s.smv[1], s.smn[1], sh.red); return; }
    if (b < s.e[SEG_SM2]) { softmax_vec(s.smv[2], s.smn[2], sh.red); return; }
}

// ---------------- y GEMM with fused blend (ex-k_fin) + stats ----------------
// w arrays are already log-softmaxed in-place; blend formulas identical to k_fin.
__global__ __launch_bounds__(256)
void k_ygemm(const float* __restrict__ wdI, const float* __restrict__ wdR,
             const float* __restrict__ wdS, const float* __restrict__ wpI,
             const float* __restrict__ wpR,
             const float* __restrict__ eiI, const float* __restrict__ eiR,
             const float* __restrict__ eiS,
             const float* __restrict__ pjI, const float* __restrict__ pjR,
             int M, int N, float* __restrict__ y, double* __restrict__ stats)
{
    __shared__ float Ast[32][65];
    __shared__ float Bst[32][65];
    __shared__ float wa[64], wb[64], wc[64], pa[64];
    __shared__ double r1[256];
    __shared__ double r2[256];
    int i0 = blockIdx.y * 64, j0 = blockIdx.x * 64;
    if (threadIdx.x < 64) {
        int i = i0 + threadIdx.x;
        if (i < M) {
            float aL = wdI[i], bL = wdR[i], cL = wdS[i];
            float x = aL / (aL + bL + cL);
            float yv = bL / (x + bL + cL);
            wa[threadIdx.x] = x; wb[threadIdx.x] = yv; wc[threadIdx.x] = 1.0f - x - yv;
        }
    } else if (threadIdx.x < 128) {
        int j = j0 + (threadIdx.x - 64);
        if (j < N) {
            float u = wpI[j], v = wpR[j];
            pa[threadIdx.x - 64] = u / (u + v);
        }
    }
    __syncthreads();
    int tx = threadIdx.x & 15, ty = threadIdx.x >> 4;
    float acc[4][4] = {};
    for (int k0 = 0; k0 < 128; k0 += 32) {
        for (int e = threadIdx.x; e < 64 * 32; e += 256) {
            int r = e >> 5, kk = e & 31;
            int ia = i0 + r, jb = j0 + r;
            long oa = (long)ia * 128 + k0 + kk;
            long ob = (long)jb * 128 + k0 + kk;
            Ast[kk][r] = (ia < M)
                ? wa[r] * eiI[oa] + wb[r] * eiR[oa] + wc[r] * eiS[oa] : 0.0f;
            Bst[kk][r] = (jb < N)
                ? pa[r] * pjI[ob] + (1.0f - pa[r]) * pjR[ob] : 0.0f;
        }
        __syncthreads();
        #pragma unroll 8
        for (int kk = 0; kk < 32; ++kk) {
            float a0 = Ast[kk][ty];      float a1 = Ast[kk][ty + 16];
            float a2 = Ast[kk][ty + 32]; float a3 = Ast[kk][ty + 48];
            float b0 = Bst[kk][tx];      float b1 = Bst[kk][tx + 16];
            float b2 = Bst[kk][tx + 32]; float b3 = Bst[kk][tx + 48];
            acc[0][0] += a0 * b0; acc[0][1] += a0 * b1; acc[0][2] += a0 * b2; acc[0][3] += a0 * b3;
            acc[1][0] += a1 * b0; acc[1][1] += a1 * b1; acc[1][2] += a1 * b2; acc[1][3] += a1 * b3;
            acc[2][0] += a2 * b0; acc[2][1] += a2 * b1; acc[2][2] += a2 * b2; acc[2][3] += a2 * b3;
            acc[3][0] += a3 * b0; acc[3][1] += a3 * b1; acc[3][2] += a3 * b2; acc[3][3] += a3 * b3;
        }
        __syncthreads();
    }
    double s1 = 0.0, s2 = 0.0;
    #pragma unroll
    for (int q = 0; q < 4; ++q) {
        int i = i0 + ty + 16 * q;
        if (i < M) {
            #pragma unroll
            for (int p = 0; p < 4; ++p) {
                int j = j0 + tx + 16 * p;
                if (j < N) {
                    float v = acc[q][p];
                    y[(long)i * N + j] = v;
                    s1 += v; s2 += (double)v * v;
                }
            }
        }
    }
    r1[threadIdx.x] = s1; r2[threadIdx.x] = s2;
    __syncthreads();
    for (int o = 128; o > 0; o >>= 1) {
        if (threadIdx.x < o) {
            r1[threadIdx.x] += r1[threadIdx.x + o];
            r2[threadIdx.x] += r2[threadIdx.x + o];
        }
        __syncthreads();
    }
    if (threadIdx.x == 0) {
        atomicAdd(&stats[0], r1[0]);
        atomicAdd(&stats[1], r2[0]);
    }
}

__global__ void k_sigmoid(const float* __restrict__ y, const double* __restrict__ stats,
                          long n4, float* __restrict__ out)
{
    long i = (long)blockIdx.x * 256 + threadIdx.x;
    if (i >= n4) return;
    double nd = (double)(n4 * 4);
    double mean = stats[0] / nd;
    double var = (stats[1] - nd * mean * mean) / (nd - 1.0);
    if (var < 1e-30) var = 1e-30;
    float inv = (float)(1.0 / sqrt(var));
    float mu = (float)mean;
    float4 v = ((const float4*)y)[i];
    v.x = 1.0f / (1.0f + expf(-((v.x - mu) * inv)));
    v.y = 1.0f / (1.0f + expf(-((v.y - mu) * inv)));
    v.z = 1.0f / (1.0f + expf(-((v.z - mu) * inv)));
    v.w = 1.0f / (1.0f + expf(-((v.w - mu) * inv)));
    ((float4*)out)[i] = v;
}

// ==================================================================
extern "C" void kernel_launch(void* const* d_in, const int* in_sizes, int n_in,
                              void* d_out, int out_size, void* d_ws, size_t ws_size,
                              hipStream_t stream)
{
    constexpr int D = 1500, P = 4500, E = 128;
    constexpr int NB = D + P;          // 6000 bipartite rows
    constexpr int NR = D + P + D;      // 7500 stacked rel rows [A2; A3; A4]
    constexpr long ALD = 6000;
    constexpr long ASZ = 36000000L;

    const float* A    = (const float*)d_in[0];
    const float* drug_structure    = (const float*)d_in[1];
    const float* protein_structure = (const float*)d_in[2];
    const float* lin_drug_w = (const float*)d_in[3];
    const float* lin_drug_b = (const float*)d_in[4];
    const float* lin_pro_w  = (const float*)d_in[5];
    const float* lin_pro_b  = (const float*)d_in[6];
    const float* p_weight   = (const float*)d_in[7];
    const float* d_weight_i = (const float*)d_in[8];
    const float* pd_weight_p = (const float*)d_in[9];
    const float* pd_weight_d = (const float*)d_in[10];
    const float* dp_weight_p = (const float*)d_in[11];
    const float* WA_drug = (const float*)d_in[12];
    const float* BA_drug = (const float*)d_in[13];
    const float* HA_drug = (const float*)d_in[14];
    const float* WB_drug = (const float*)d_in[15];
    const float* BB_drug = (const float*)d_in[16];
    const float* HB_drug = (const float*)d_in[17];
    const float* WA_pro = (const float*)d_in[18];
    const float* BA_pro = (const float*)d_in[19];
    const float* HA_pro = (const float*)d_in[20];
    const float* WB_pro = (const float*)d_in[21];
    const float* BB_pro = (const float*)d_in[22];
    const float* HB_pro = (const float*)d_in[23];
    const float* WA_sim = (const float*)d_in[24];
    const float* BA_sim = (const float*)d_in[25];
    const float* HA_sim = (const float*)d_in[26];
    // d_in[27] = layer (int), fixed 3.

    const float* Rp  = A + 1500;                          // [D x P]   ld 6000
    const float* A2p = A + 2 * ASZ;                       // [D x D]
    const float* A3p = A + 3 * ASZ + 1500 * ALD + 1500;   // [P x P]
    const float* A4p = A + 4 * ASZ;                       // [D x D]

    char* wsbase = (char*)d_ws;
    size_t off = 0;
    auto alloc = [&](size_t bytes) -> void* {
        off = (off + 255) & ~(size_t)255;
        void* p = wsbase + off;
        off += bytes;
        return p;
    };
    int*   idx_bip  = (int*)alloc((size_t)NB * CAP * 4);
    int*   cnt_bip  = (int*)alloc((size_t)NB * 4);
    int*   idx_rel  = (int*)alloc((size_t)NR * CAP * 4);
    int*   cnt_rel  = (int*)alloc((size_t)NR * 4);
    float* str_s    = (float*)alloc((size_t)NR * E * 4);
    float* nei_s    = (float*)alloc((size_t)NR * E * 4);
    float* cur_s    = (float*)alloc((size_t)NR * E * 4);
    float* nxt_s    = (float*)alloc((size_t)NR * E * 4);
    float* acc_s    = (float*)alloc((size_t)NR * E * 4);
    float* emb_s    = (float*)alloc((size_t)NR * E * 4);
    float* tem_s    = (float*)alloc((size_t)NB * E * 4);
    float* big_cur  = (float*)alloc((size_t)2 * NB * E * 4);
    float* big_nxt  = (float*)alloc((size_t)2 * NB * E * 4);
    float* big_acc  = (float*)alloc((size_t)2 * NB * E * 4);
    float* int_s    = (float*)alloc((size_t)2 * NB * E * 4);
    float* W2       = (float*)alloc((size_t)E * E * 4);
    float* w_drug = (float*)alloc(D * 4);
    float* w_drel = (float*)alloc(D * 4);
    float* w_dsim = (float*)alloc(D * 4);
    float* w_pro  = (float*)alloc(P * 4);
    float* w_prel = (float*)alloc(P * 4);
    float* ybuf    = (float*)alloc((size_t)D * P * 4);
    double* stats  = (double*)alloc(2 * sizeof(double));
    (void)ws_size; (void)in_sizes; (void)n_in; (void)out_size;

    float* dru_str = str_s;
    float* pro_str = str_s + (size_t)D * E;
    float* dru_rel_emb = emb_s;
    float* pro_rel_emb = emb_s + (size_t)D * E;
    float* dru_sim_emb = emb_s + (size_t)NB * E;
    float* dru_tem = tem_s;
    float* pro_tem = tem_s + (size_t)D * E;
    float* dru_int = int_s;
    float* pro_int = int_s + (size_t)(NB + D) * E;

    long nD = (long)D * E;

    auto launch_stage = [&](Stage& s, const int* sz) {
        int tot = 0;
        for (int i = 0; i < NSEG; ++i) { tot += sz[i]; s.e[i] = tot; }
        k_stage<<<tot, 256, 0, stream>>>(s);
    };

    // ---- Stage 1: zero counters/stats + build 4 CSRs + projections + W2 ----
    {
        Stage s = {};
        int sz[NSEG] = {};
        sz[SEG_ZERO] = (P + 255) / 256;
        s.nZero = P; s.zeroPtr = cnt_bip + D; s.stats = stats;
        s.bs[0] = { Rp,  ALD, D, P, D,  idx_bip, cnt_bip };                        sz[SEG_B0] = (D + 3) / 4;
        s.bs[1] = { A2p, ALD, D, D, 0,  idx_rel, cnt_rel };                        sz[SEG_B1] = (D + 3) / 4;
        s.bs[2] = { A3p, ALD, P, P, D,  idx_rel + (size_t)D * CAP,  cnt_rel + D }; sz[SEG_B2] = (P + 3) / 4;
        s.bs[3] = { A4p, ALD, D, D, NB, idx_rel + (size_t)NB * CAP, cnt_rel + NB };sz[SEG_B3] = (D + 3) / 4;
        s.lin[0] = { drug_structure, nullptr, 0, 0, D, 160, lin_drug_w, lin_drug_b,
                     dru_str, str_s + (size_t)NB * E };                            sz[SEG_LIN0] = (D + 1) / 2;
        s.lin[1] = { protein_structure, nullptr, 0, 0, P, 512, lin_pro_w, lin_pro_b,
                     pro_str, nullptr };                                           sz[SEG_LIN1] = (P + 1) / 2;
        s.lin[2] = { dp_weight_p, nullptr, 0, 0, E, E, pd_weight_d, nullptr, W2, nullptr };
                                                                                   sz[SEG_LIN2] = (E + 1) / 2;
        launch_stage(s, sz);
    }
    // ---- Stage 2: scatter transpose + rel neighbor means + rel GCN inits ----
    {
        Stage s = {};
        int sz[NSEG] = {};
        s.scatterTop = D; s.sIdx = idx_bip; s.sCnt = cnt_bip;                      sz[SEG_SCAT] = (D + 3) / 4;
        s.sp[0] = { idx_rel, cnt_rel, NR, NR, str_s, nei_s, nullptr, nullptr, nullptr, RS_INV };
                                                                                   sz[SEG_SP0] = (NR + 7) / 8;
        s.lin[0] = { dru_str, nullptr, 0, 0, D, E, d_weight_i, nullptr,
                     cur_s, cur_s + (size_t)NB * E };                              sz[SEG_LIN0] = (D + 1) / 2;
        s.lin[1] = { pro_str, nullptr, 0, 0, P, E, p_weight, nullptr,
                     cur_s + (size_t)D * E, nullptr };                             sz[SEG_LIN1] = (P + 1) / 2;
        launch_stage(s, sz);
    }
    // ---- Stage 3: rel L1 || bipartite neighbor means ----
    {
        Stage s = {};
        int sz[NSEG] = {};
        s.sp[0] = { idx_rel, cnt_rel, NR, NR, cur_s, nxt_s, acc_s, cur_s, nullptr,
                    RS_RSQRT | CS_RSQRT };                                         sz[SEG_SP0] = (NR + 7) / 8;
        s.sp[1] = { idx_bip, cnt_bip, NB, NB, nei_s, tem_s, nullptr, nullptr, nullptr,
                    RS_INV };                                                      sz[SEG_SP1] = (NB + 7) / 8;
        launch_stage(s, sz);
    }
    // ---- Stage 4: rel L2 || bipartite GCN inits ----
    {
        Stage s = {};
        int sz[NSEG] = {};
        s.sp[0] = { idx_rel, cnt_rel, NR, NR, nxt_s, cur_s, acc_s, nullptr, nullptr,
                    RS_RSQRT | CS_RSQRT };                                         sz[SEG_SP0] = (NR + 7) / 8;
        s.lin[0] = { dru_str, nullptr, 0, 0, D, E, pd_weight_d, nullptr, big_cur, nullptr };
                                                                                   sz[SEG_LIN0] = (D + 1) / 2;
        s.lin[1] = { pro_str, pro_tem, 0.8f, 0.2f, P, E, W2, nullptr, big_cur + nD, nullptr };
                                                                                   sz[SEG_LIN1] = (P + 1) / 2;
        s.lin[2] = { dru_str, dru_tem, 0.8f, 0.2f, D, E, nullptr, nullptr,
                     big_cur + (size_t)NB * E, nullptr };                          sz[SEG_LIN2] = (D + 1) / 2;
        s.lin[3] = { pro_str, nullptr, 0, 0, P, E, pd_weight_p, nullptr,
                     big_cur + (size_t)(NB + D) * E, nullptr };                    sz[SEG_LIN3] = (P + 1) / 2;
        launch_stage(s, sz);
    }
    // ---- Stage 5: bip L1 || rel L3 (finalize -> emb) ----
    {
        Stage s = {};
        int sz[NSEG] = {};
        s.sp[0] = { idx_bip, cnt_bip, 2 * NB, NB, big_cur, big_nxt, big_acc, big_cur,
                    nullptr, RS_RSQRT | CS_RSQRT };                                sz[SEG_SP0] = (2 * NB + 7) / 8;
        s.sp[1] = { idx_rel, cnt_rel, NR, NR, cur_s, nullptr, acc_s, nullptr, emb_s,
                    RS_RSQRT | CS_RSQRT | FINALIZE };                              sz[SEG_SP1] = (NR + 7) / 8;
        launch_stage(s, sz);
    }
    // ---- Stage 6: bip L2 || rel attention scores ----
    {
        Stage s = {};
        int sz[NSEG] = {};
        s.sp[0] = { idx_bip, cnt_bip, 2 * NB, NB, big_nxt, big_cur, big_acc, nullptr,
                    nullptr, RS_RSQRT | CS_RSQRT };                                sz[SEG_SP0] = (2 * NB + 7) / 8;
        s.at[0] = { dru_rel_emb, D, WB_drug, BB_drug, HB_drug, w_drel };           sz[SEG_AT0] = (D + 1) / 2;
        s.at[1] = { pro_rel_emb, P, WB_pro,  BB_pro,  HB_pro,  w_prel };           sz[SEG_AT1] = (P + 1) / 2;
        s.at[2] = { dru_sim_emb, D, WA_sim,  BA_sim,  HA_sim,  w_dsim };           sz[SEG_AT2] = (D + 1) / 2;
        launch_stage(s, sz);
    }
    // ---- Stage 7: bip L3 (finalize -> int) || softmax of rel scores ----
    {
        Stage s = {};
        int sz[NSEG] = {};
        s.sp[0] = { idx_bip, cnt_bip, 2 * NB, NB, big_cur, nullptr, big_acc, nullptr,
                    int_s, RS_RSQRT | CS_RSQRT | FINALIZE };                       sz[SEG_SP0] = (2 * NB + 7) / 8;
        s.smv[0] = w_drel; s.smn[0] = D;                                           sz[SEG_SM0] = 1;
        s.smv[1] = w_prel; s.smn[1] = P;                                           sz[SEG_SM1] = 1;
        s.smv[2] = w_dsim; s.smn[2] = D;                                           sz[SEG_SM2] = 1;
        launch_stage(s, sz);
    }
    // ---- Stage 8: int attention scores ----
    {
        Stage s = {};
        int sz[NSEG] = {};
        s.at[0] = { dru_int, D, WA_drug, BA_drug, HA_drug, w_drug };               sz[SEG_AT0] = (D + 1) / 2;
        s.at[1] = { pro_int, P, WA_pro,  BA_pro,  HA_pro,  w_pro  };               sz[SEG_AT1] = (P + 1) / 2;
        launch_stage(s, sz);
    }
    // ---- Stage 9: softmax of int scores ----
    {
        Stage s = {};
        int sz[NSEG] = {};
        s.smv[0] = w_drug; s.smn[0] = D;                                           sz[SEG_SM0] = 1;
        s.smv[1] = w_pro;  s.smn[1] = P;                                           sz[SEG_SM1] = 1;
        launch_stage(s, sz);
    }
    // ---- y GEMM with fused blend + stats, then standardize + sigmoid ----
    dim3 yg((P + 63) / 64, (D + 63) / 64);
    k_ygemm<<<yg, 256, 0, stream>>>(w_drug, w_drel, w_dsim, w_pro, w_prel,
                                    dru_int, dru_rel_emb, dru_sim_emb,
                                    pro_int, pro_rel_emb,
                                    D, P, ybuf, stats);
    long n4 = ((long)D * P) >> 2;
    k_sigmoid<<<(int)((n4 + 255) / 256), 256, 0, stream>>>(ybuf, stats, n4, (float*)d_out);
}